// Round 3
// baseline (87720.471 us; speedup 1.0000x reference)
//
#include <hip/hip_runtime.h>
#include <math.h>

// ---------------- problem constants ----------------
constexpr int MM = 8;      // batch of GPs
constexpr int NC = 1024;   // context points
constexpr int NT = 512;    // target points

// Workspace layout (floats):
//  Kb   : MM*1024*1024   (K -> L panels -> G = K^-1)
//  Ab   : MM*1024*1024   (diag-block inverses + A = L^-1; reused as W at predict)
//  Tb   : MM*512*512     (trinv temp)
//  Ktc  : MM*NT*NC
//  alpha: MM*1024
//  scal : MM*32  per-m: [0..3] raw params [4..7] adam m [8..11] adam v
//                       [12]ls [13]os [14]noise [15]T1 [16]T2
//  bar  : MM*128 u32 (per-m barrier state: 4 sub-counters @0/16/32/48, root @64, gen @80)
constexpr size_t OFF_A     = (size_t)MM * 1024 * 1024;
constexpr size_t OFF_T     = OFF_A * 2;
constexpr size_t OFF_KTC   = OFF_T + (size_t)MM * 512 * 512;
constexpr size_t OFF_ALPHA = OFF_KTC + (size_t)MM * NT * NC;
constexpr size_t OFF_SCAL  = OFF_ALPHA + (size_t)MM * 1024;
constexpr size_t OFF_BAR   = OFF_SCAL + (size_t)MM * 32;

#define S5 2.2360679775f

__device__ __forceinline__ float sigmf(float x) { return 1.0f / (1.0f + expf(-x)); }
__device__ __forceinline__ float softplusf(float x) { return fmaxf(x, 0.0f) + log1pf(expf(-fabsf(x))); }

__device__ __forceinline__ void lt_decode(int x, int& i, int& j) {
  int ii = 0;
  while ((ii + 1) * (ii + 2) / 2 <= x) ++ii;
  i = ii; j = x - ii * (ii + 1) / 2;
}

// Shared-memory struct for all phases (~47.5 KB -> 2+ blocks/CU)
struct SMem {
  float Ls[64 * 65];
  float Us[64 * 65];
  float Tt[32 * 33];
  float dvec[64];
  float As[16][68];
  float Bs[16][68];
  float xi[64][3];
  float xj[64][3];
  float ai[64];
  float aj[64];
  float red[4][4];
};

// ---------------- per-m grid barrier: 64 blocks, 4 padded sub-counters -------
__device__ __forceinline__ void gbar(unsigned* barm, int lb, int& epoch) {
  __syncthreads();
  if (threadIdx.x == 0) {
    unsigned e1 = (unsigned)(epoch + 1);
    __threadfence();
    unsigned* ctr = barm + ((lb & 3) << 4);          // 64B-padded counters
    unsigned old = __hip_atomic_fetch_add(ctr, 1u, __ATOMIC_ACQ_REL, __HIP_MEMORY_SCOPE_AGENT);
    if (old + 1u == 16u * e1) {
      unsigned r = __hip_atomic_fetch_add(barm + 64, 1u, __ATOMIC_ACQ_REL, __HIP_MEMORY_SCOPE_AGENT);
      if (r + 1u == 4u * e1) {
        __hip_atomic_store(barm + 80, e1, __ATOMIC_RELEASE, __HIP_MEMORY_SCOPE_AGENT);
      }
    }
    while (__hip_atomic_load(barm + 80, __ATOMIC_ACQUIRE, __HIP_MEMORY_SCOPE_AGENT) < e1) {
      __builtin_amdgcn_s_sleep(2);
    }
    __threadfence();
  }
  __syncthreads();
  epoch += 1;
}

// ---------------- generic 64x64-tile GEMM over K (LDS staged, 4x4 microtile) --
// logical A(r,k): TA ? A[k*lda+r] : A[r*lda+k];  logical B(k,c): TB ? B[c*ldb+k] : B[k*ldb+c]
template <int TA, int TB>
__device__ __forceinline__ void gemm64(const float* __restrict__ A, int lda,
                                       const float* __restrict__ B, int ldb,
                                       int kBeg, int kEnd, float acc[4][4], SMem& sm) {
  int tid = threadIdx.x, tx = tid & 15, ty = tid >> 4;
  for (int k0 = kBeg; k0 < kEnd; k0 += 16) {
    __syncthreads();
    if (TA) {
      for (int e = tid; e < 1024; e += 256) { int kk = e >> 6, r = e & 63; sm.As[kk][r] = A[(size_t)(k0 + kk) * lda + r]; }
    } else {
      for (int e = tid; e < 1024; e += 256) { int r = e >> 4, kk = e & 15; sm.As[kk][r] = A[(size_t)r * lda + k0 + kk]; }
    }
    if (TB) {
      for (int e = tid; e < 1024; e += 256) { int c = e >> 4, kk = e & 15; sm.Bs[kk][c] = B[(size_t)c * ldb + k0 + kk]; }
    } else {
      for (int e = tid; e < 1024; e += 256) { int kk = e >> 6, c = e & 63; sm.Bs[kk][c] = B[(size_t)(k0 + kk) * ldb + c]; }
    }
    __syncthreads();
#pragma unroll
    for (int kk = 0; kk < 16; ++kk) {
      float a[4], b[4];
#pragma unroll
      for (int i = 0; i < 4; ++i) a[i] = sm.As[kk][ty * 4 + i];
#pragma unroll
      for (int j = 0; j < 4; ++j) b[j] = sm.Bs[kk][tx * 4 + j];
#pragma unroll
      for (int i = 0; i < 4; ++i)
#pragma unroll
        for (int j = 0; j < 4; ++j) acc[i][j] = fmaf(a[i], b[j], acc[i][j]);
    }
  }
}

// ---------------- in-LDS 64x64 SPD factor + triangular inverse ---------------
// input: sm.Ls holds raw SPD tile (stride 65). writes Linv (full 64x64, upper=0)
// to Uout with row stride ldu. (L itself is never needed outside.)
__device__ void factor64(SMem& sm, float* Uout, int ldu) {
  int tid = threadIdx.x;
  int tx = tid & 15, ty = tid >> 4;
  // raw Schur-complement loop: 1 barrier per column
  for (int j = 0; j < 63; ++j) {
    float rinv = 1.0f / sm.Ls[j * 65 + j];
    for (int i = j + 1 + ty; i < 64; i += 16) {
      float lij = sm.Ls[i * 65 + j] * rinv;
      for (int c = j + 1 + tx; c <= i; c += 16) sm.Ls[i * 65 + c] -= lij * sm.Ls[c * 65 + j];
    }
    __syncthreads();
  }
  if (tid < 64) sm.dvec[tid] = 1.0f / sqrtf(sm.Ls[tid * 65 + tid]);
  __syncthreads();
  for (int e = tid; e < 4096; e += 256) { int r = e >> 6, c = e & 63; if (c <= r) sm.Ls[r * 65 + c] *= sm.dvec[c]; }
  __syncthreads();
  for (int e = tid; e < 64 * 65; e += 256) sm.Us[e] = 0.0f;
  __syncthreads();
  // two 32x32 base inverses (thread-per-column)
  if (tid < 64) {
    int b = tid >> 5, c0 = tid & 31, base = b * 32, gc = base + c0;
    sm.Us[gc * 65 + gc] = 1.0f / sm.Ls[gc * 65 + gc];
    for (int r = c0 + 1; r < 32; ++r) {
      int gr = base + r;
      float acc = 0.0f;
      for (int l = c0; l < r; ++l) acc += sm.Ls[gr * 65 + base + l] * sm.Us[(base + l) * 65 + gc];
      sm.Us[gr * 65 + gc] = -acc / sm.Ls[gr * 65 + gr];
    }
  }
  __syncthreads();
  // one doubling step: T = L21*U11; U21 = -U22*T
  for (int e = tid; e < 1024; e += 256) {
    int r = e >> 5, c = e & 31;
    float acc = 0.0f;
    for (int l = c; l < 32; ++l) acc += sm.Ls[(32 + r) * 65 + l] * sm.Us[l * 65 + c];
    sm.Tt[r * 33 + c] = acc;
  }
  __syncthreads();
  for (int e = tid; e < 1024; e += 256) {
    int r = e >> 5, c = e & 31;
    float acc = 0.0f;
    for (int l = 0; l <= r; ++l) acc += sm.Us[(32 + r) * 65 + 32 + l] * sm.Tt[l * 33 + c];
    sm.Us[(32 + r) * 65 + c] = -acc;
  }
  __syncthreads();
  for (int e = tid; e < 4096; e += 256) { int r = e >> 6, c = e & 63; Uout[(size_t)r * ldu + c] = sm.Us[r * 65 + c]; }
}

// ---------------- phases (all per-m: 64 blocks, local id lb) -----------------

// Build K lower tiles; fuse factor of tile (0,0); zero alpha + T1/T2.
__device__ void ph_buildK(SMem& sm, const float* xm, float* Km, float* Am,
                          float* sT, float* al, int n, int nb, int lb) {
  int tid = threadIdx.x;
  {
    int zi = (lb - 1) * 256 + tid;
    if (lb >= 1 && lb <= 4 && zi < n) al[zi] = 0.0f;
    if (lb == 5 && tid < 2) sT[15 + tid] = 0.0f;
  }
  float ls = sT[12], os = sT[13], noi = sT[14];
  float il2 = 1.0f / (ls * ls);
  int njobs = nb * (nb + 1) / 2;
  for (int job = lb; job < njobs; job += 64) {
    int bi, bj; lt_decode(job, bi, bj);
    __syncthreads();
    if (tid < 64) {
      int r = bi * 64 + tid;
      sm.xi[tid][0] = xm[r * 3 + 0]; sm.xi[tid][1] = xm[r * 3 + 1]; sm.xi[tid][2] = xm[r * 3 + 2];
    } else if (tid < 128) {
      int lr = tid - 64; int r = bj * 64 + lr;
      sm.xj[lr][0] = xm[r * 3 + 0]; sm.xj[lr][1] = xm[r * 3 + 1]; sm.xj[lr][2] = xm[r * 3 + 2];
    }
    __syncthreads();
    if (job == 0) {
      // tile (0,0): build in LDS, factor + invert immediately (saves a phase)
      for (int e = tid; e < 4096; e += 256) {
        int r = e >> 6, c = e & 63;
        float d0 = sm.xi[r][0] - sm.xj[c][0], d1 = sm.xi[r][1] - sm.xj[c][1], d2 = sm.xi[r][2] - sm.xj[c][2];
        float r2 = d0 * d0 + d1 * d1 + d2 * d2;
        float z = fmaxf(r2 * il2, 1e-12f);
        float dd = sqrtf(z);
        float kv = os * (1.0f + S5 * dd + (5.0f / 3.0f) * z) * expf(-S5 * dd);
        if (r == c) kv += noi;
        sm.Ls[r * 65 + c] = kv;
      }
      __syncthreads();
      factor64(sm, Am, n);
    } else {
      for (int e = tid; e < 4096; e += 256) {
        int r = e >> 6, c = e & 63;
        float d0 = sm.xi[r][0] - sm.xj[c][0], d1 = sm.xi[r][1] - sm.xj[c][1], d2 = sm.xi[r][2] - sm.xj[c][2];
        float r2 = d0 * d0 + d1 * d1 + d2 * d2;
        float z = fmaxf(r2 * il2, 1e-12f);
        float dd = sqrtf(z);
        float kv = os * (1.0f + S5 * dd + (5.0f / 3.0f) * z) * expf(-S5 * dd);
        if (bi == bj && r == c) kv += noi;
        Km[(size_t)(bi * 64 + r) * n + bj * 64 + c] = kv;
      }
    }
  }
}

// panel: L[i,k] = K[i,k] * Linv[k,k]^T (in place)
__device__ void ph_panel(SMem& sm, float* Km, const float* Am, int k, int n, int t, int lb) {
  int tx = threadIdx.x & 15, ty = threadIdx.x >> 4;
  for (int job = lb; job < t; job += 64) {
    int i = k + 1 + job;
    float acc[4][4] = {};
    gemm64<0, 1>(Km + (size_t)(i * 64) * n + k * 64, n,
                 Am + (size_t)(k * 64) * n + k * 64, n, 0, 64, acc, sm);
    float* C = Km + (size_t)(i * 64) * n + k * 64;
#pragma unroll
    for (int ii = 0; ii < 4; ++ii)
#pragma unroll
      for (int jj = 0; jj < 4; ++jj) C[(size_t)(ty * 4 + ii) * n + tx * 4 + jj] = acc[ii][jj];
  }
}

// trailing update K[i,j] -= L[i,k]*L[j,k]^T; job 0 = tile (k+1,k+1), which is
// updated in LDS and immediately factored+inverted (fused diag).
__device__ void ph_trailF(SMem& sm, float* Km, float* Am, int k, int n, int t, int lb) {
  int tx = threadIdx.x & 15, ty = threadIdx.x >> 4;
  int njobs = t * (t + 1) / 2;
  for (int job = lb; job < njobs; job += 64) {
    int di, dj; lt_decode(job, di, dj);
    int i = k + 1 + di, j = k + 1 + dj;
    float acc[4][4] = {};
    gemm64<0, 1>(Km + (size_t)(i * 64) * n + k * 64, n,
                 Km + (size_t)(j * 64) * n + k * 64, n, 0, 64, acc, sm);
    float* C = Km + (size_t)(i * 64) * n + j * 64;
    if (job == 0) {
#pragma unroll
      for (int ii = 0; ii < 4; ++ii)
#pragma unroll
        for (int jj = 0; jj < 4; ++jj)
          sm.Ls[(ty * 4 + ii) * 65 + tx * 4 + jj] =
              C[(size_t)(ty * 4 + ii) * n + tx * 4 + jj] - acc[ii][jj];
      __syncthreads();
      factor64(sm, Am + (size_t)((k + 1) * 64) * n + (k + 1) * 64, n);
    } else {
#pragma unroll
      for (int ii = 0; ii < 4; ++ii)
#pragma unroll
        for (int jj = 0; jj < 4; ++jj)
          C[(size_t)(ty * 4 + ii) * n + tx * 4 + jj] -= acc[ii][jj];
    }
  }
}

// trinv phase 1: T = L21 * A11 (A11 block-lower)
__device__ void ph_trinvT(SMem& sm, const float* Km, const float* Am, float* Tm,
                          int s, int n, int lb) {
  int tx = threadIdx.x & 15, ty = threadIdx.x >> 4;
  int st = s >> 6, np = n / (2 * s);
  int njobs = np * st * st;
  for (int job = lb; job < njobs; job += 64) {
    int p = job / (st * st), rem = job % (st * st);
    int ti = rem / st, tj = rem % st;
    int base = p * 2 * s;
    float acc[4][4] = {};
    gemm64<0, 0>(Km + (size_t)(base + s + ti * 64) * n + base, n,
                 Am + (size_t)base * n + base + tj * 64, n, tj * 64, s, acc, sm);
    float* C = Tm + (size_t)p * s * s + (size_t)(ti * 64) * s + tj * 64;
#pragma unroll
    for (int ii = 0; ii < 4; ++ii)
#pragma unroll
      for (int jj = 0; jj < 4; ++jj) C[(size_t)(ty * 4 + ii) * s + tx * 4 + jj] = acc[ii][jj];
  }
}

// trinv phase 2: A21 = -A22 * T (A22 block-lower)
__device__ void ph_trinvA(SMem& sm, float* Am, const float* Tm, int s, int n, int lb) {
  int tx = threadIdx.x & 15, ty = threadIdx.x >> 4;
  int st = s >> 6, np = n / (2 * s);
  int njobs = np * st * st;
  for (int job = lb; job < njobs; job += 64) {
    int p = job / (st * st), rem = job % (st * st);
    int ti = rem / st, tj = rem % st;
    int base = p * 2 * s;
    float acc[4][4] = {};
    gemm64<0, 0>(Am + (size_t)(base + s + ti * 64) * n + base + s, n,
                 Tm + (size_t)p * s * s + tj * 64, s, 0, (ti + 1) * 64, acc, sm);
    float* C = Am + (size_t)(base + s + ti * 64) * n + base + tj * 64;
#pragma unroll
    for (int ii = 0; ii < 4; ++ii)
#pragma unroll
      for (int jj = 0; jj < 4; ++jj) C[(size_t)(ty * 4 + ii) * n + tx * 4 + jj] = -acc[ii][jj];
  }
}

// syrk: G = A^T A (A lower-tri), lower tile + mirror
__device__ void ph_syrk(SMem& sm, const float* Am, float* Gm, int n, int nb, int lb) {
  int tx = threadIdx.x & 15, ty = threadIdx.x >> 4;
  int njobs = nb * (nb + 1) / 2;
  for (int job = lb; job < njobs; job += 64) {
    int ib, jb; lt_decode(job, ib, jb);
    float acc[4][4] = {};
    gemm64<1, 0>(Am + ib * 64, n, Am + jb * 64, n, ib * 64, n, acc, sm);
#pragma unroll
    for (int ii = 0; ii < 4; ++ii)
#pragma unroll
      for (int jj = 0; jj < 4; ++jj) {
        int r = ty * 4 + ii, c = tx * 4 + jj;
        Gm[(size_t)(ib * 64 + r) * n + jb * 64 + c] = acc[ii][jj];
        if (ib != jb) Gm[(size_t)(jb * 64 + c) * n + ib * 64 + r] = acc[ii][jj];
      }
  }
}

// alpha += per-column-block contribution of G * (y - const)
__device__ void ph_alpha(SMem& sm, const float* Gm, const float* ym, const float* sT,
                         float* al, int n, int nb, int lb) {
  int tid = threadIdx.x;
  int NQ = n >> 8;  // 2 or 4
  for (int job = lb; job < nb; job += 64) {
    int cb = job;
    __syncthreads();
    if (tid < 64) sm.ai[tid] = ym[cb * 64 + tid] - sT[3];
    __syncthreads();
    float acc[4] = {0.f, 0.f, 0.f, 0.f};
    for (int c = 0; c < 64; ++c) {
      float yv = sm.ai[c];
      const float* row = Gm + (size_t)(cb * 64 + c) * n;
#pragma unroll
      for (int q = 0; q < 4; ++q)
        if (q < NQ) acc[q] = fmaf(row[tid + (q << 8)], yv, acc[q]);
    }
#pragma unroll
    for (int q = 0; q < 4; ++q)
      if (q < NQ) atomicAdd(&al[tid + (q << 8)], acc[q]);
  }
}

// reduce: T1 = sum G.*C, T2 = alpha^T C alpha (symmetric: lower-tri * weight)
__device__ void ph_reduce(SMem& sm, const float* Gm, const float* xm, const float* al,
                          float* sT, int n, int nb, int lb) {
  int tid = threadIdx.x;
  int njobs = nb * (nb + 1) / 2;
  float ls = sT[12], os = sT[13];
  float il2 = 1.0f / (ls * ls);
  float c53 = (5.0f / 3.0f) * os / ls;
  for (int job = lb; job < njobs; job += 64) {
    int bi, bj; lt_decode(job, bi, bj);
    float w = (bi == bj) ? 1.0f : 2.0f;
    __syncthreads();
    if (tid < 64) {
      int r = bi * 64 + tid;
      sm.xi[tid][0] = xm[r * 3 + 0]; sm.xi[tid][1] = xm[r * 3 + 1]; sm.xi[tid][2] = xm[r * 3 + 2];
      sm.ai[tid] = al[r];
    } else if (tid < 128) {
      int lr = tid - 64; int r = bj * 64 + lr;
      sm.xj[lr][0] = xm[r * 3 + 0]; sm.xj[lr][1] = xm[r * 3 + 1]; sm.xj[lr][2] = xm[r * 3 + 2];
      sm.aj[lr] = al[r];
    }
    __syncthreads();
    float a1 = 0.0f, a2 = 0.0f;
    for (int e = tid; e < 4096; e += 256) {
      int r = e >> 6, c = e & 63;
      float d0 = sm.xi[r][0] - sm.xj[c][0], d1 = sm.xi[r][1] - sm.xj[c][1], d2 = sm.xi[r][2] - sm.xj[c][2];
      float r2 = d0 * d0 + d1 * d1 + d2 * d2;
      float z = fmaxf(r2 * il2, 1e-12f);
      float dd = sqrtf(z);
      float Cv = c53 * z * (1.0f + S5 * dd) * expf(-S5 * dd);
      float g = Gm[(size_t)(bi * 64 + r) * n + bj * 64 + c];
      a1 = fmaf(g, Cv, a1);
      a2 = fmaf(sm.ai[r] * sm.aj[c], Cv, a2);
    }
    a1 *= w; a2 *= w;
    for (int off = 32; off; off >>= 1) { a1 += __shfl_down(a1, off); a2 += __shfl_down(a2, off); }
    int wid = tid >> 6, lane = tid & 63;
    if (lane == 0) { sm.red[wid][0] = a1; sm.red[wid][1] = a2; }
    __syncthreads();
    if (tid == 0) {
      a1 = sm.red[0][0] + sm.red[1][0] + sm.red[2][0] + sm.red[3][0];
      a2 = sm.red[0][1] + sm.red[1][1] + sm.red[2][1] + sm.red[3][1];
      atomicAdd(&sT[15], a1);
      atomicAdd(&sT[16], a2);
    }
  }
}

// adam: finish reductions, compute grads, update params (block 0 of partition)
__device__ void ph_adam(SMem& sm, const float* Gm, const float* ym, const float* al,
                        float* sT, int n, int tstep, int lb) {
  if (lb != 0) return;
  int tid = threadIdx.x;
  float cm = sT[3];
  float t3 = 0, t4 = 0, t5 = 0, t6 = 0;
  for (int i = tid; i < n; i += 256) {
    float a = al[i];
    t3 += Gm[(size_t)i * n + i];
    t4 = fmaf(a, a, t4);
    t5 += a;
    t6 = fmaf(ym[i] - cm, a, t6);
  }
  for (int off = 32; off; off >>= 1) {
    t3 += __shfl_down(t3, off); t4 += __shfl_down(t4, off);
    t5 += __shfl_down(t5, off); t6 += __shfl_down(t6, off);
  }
  int wid = tid >> 6, lane = tid & 63;
  __syncthreads();
  if (lane == 0) { sm.red[wid][0] = t3; sm.red[wid][1] = t4; sm.red[wid][2] = t5; sm.red[wid][3] = t6; }
  __syncthreads();
  if (tid == 0) {
    t3 = sm.red[0][0] + sm.red[1][0] + sm.red[2][0] + sm.red[3][0];
    t4 = sm.red[0][1] + sm.red[1][1] + sm.red[2][1] + sm.red[3][1];
    t5 = sm.red[0][2] + sm.red[1][2] + sm.red[2][2] + sm.red[3][2];
    t6 = sm.red[0][3] + sm.red[1][3] + sm.red[2][3] + sm.red[3][3];
    float T1 = sT[15], T2 = sT[16];
    float ls = sT[12], os = sT[13], noi = sT[14];
    float fn = (float)n;
    float g_ls = 0.5f / fn * (T1 - T2);
    float g_os = 0.5f / (fn * os) * (fn - noi * t3 - t6 + noi * t4);
    float g_no = 0.5f / fn * (t3 - t4);
    float g_c  = -t5 / fn;
    float gr[4];
    gr[0] = g_ls * sigmf(sT[0]);
    gr[1] = g_os * sigmf(sT[1]);
    gr[2] = g_no * sigmf(sT[2]);
    gr[3] = g_c;
    float bc1 = 1.0f - powf(0.9f, (float)tstep);
    float bc2 = 1.0f - powf(0.999f, (float)tstep);
#pragma unroll
    for (int i = 0; i < 4; ++i) {
      float mv = 0.9f * sT[4 + i] + 0.1f * gr[i];
      float vv = 0.999f * sT[8 + i] + 0.001f * gr[i] * gr[i];
      sT[4 + i] = mv; sT[8 + i] = vv;
      sT[i] = sT[i] - 0.1f * (mv / bc1) / (sqrtf(vv / bc2) + 1e-8f);
    }
    sT[12] = softplusf(sT[0]);
    sT[13] = softplusf(sT[1]);
    sT[14] = softplusf(sT[2]) + 1e-4f;
  }
}

// prediction
__device__ void ph_buildKtc(SMem& sm, const float* xtm, const float* xm, float* Kt,
                            const float* sT, int lb) {
  int tid = threadIdx.x;
  float ls = sT[12], os = sT[13];
  float il2 = 1.0f / (ls * ls);
  int njobs = (NT / 64) * (NC / 64);  // 8*16 = 128
  for (int job = lb; job < njobs; job += 64) {
    int ti = job >> 4, tj = job & 15;
    __syncthreads();
    if (tid < 64) {
      int r = ti * 64 + tid;
      sm.xi[tid][0] = xtm[r * 3 + 0]; sm.xi[tid][1] = xtm[r * 3 + 1]; sm.xi[tid][2] = xtm[r * 3 + 2];
    } else if (tid < 128) {
      int lr = tid - 64; int r = tj * 64 + lr;
      sm.xj[lr][0] = xm[r * 3 + 0]; sm.xj[lr][1] = xm[r * 3 + 1]; sm.xj[lr][2] = xm[r * 3 + 2];
    }
    __syncthreads();
    for (int e = tid; e < 4096; e += 256) {
      int r = e >> 6, c = e & 63;
      float d0 = sm.xi[r][0] - sm.xj[c][0], d1 = sm.xi[r][1] - sm.xj[c][1], d2 = sm.xi[r][2] - sm.xj[c][2];
      float r2 = d0 * d0 + d1 * d1 + d2 * d2;
      float z = fmaxf(r2 * il2, 1e-12f);
      float dd = sqrtf(z);
      float kv = os * (1.0f + S5 * dd + (5.0f / 3.0f) * z) * expf(-S5 * dd);
      Kt[(size_t)(ti * 64 + r) * NC + tj * 64 + c] = kv;
    }
  }
}

__device__ void ph_predW(SMem& sm, const float* Kt, const float* Gm, float* Wm, int lb) {
  int tx = threadIdx.x & 15, ty = threadIdx.x >> 4;
  int njobs = (NT / 64) * (NC / 64);
  for (int job = lb; job < njobs; job += 64) {
    int ti = job >> 4, tj = job & 15;
    float acc[4][4] = {};
    gemm64<0, 0>(Kt + (size_t)(ti * 64) * NC, NC, Gm + tj * 64, 1024, 0, 1024, acc, sm);
    float* C = Wm + (size_t)(ti * 64) * NC + tj * 64;
#pragma unroll
    for (int ii = 0; ii < 4; ++ii)
#pragma unroll
      for (int jj = 0; jj < 4; ++jj) C[(size_t)(ty * 4 + ii) * NC + tx * 4 + jj] = acc[ii][jj];
  }
}

__device__ void ph_meanvar(SMem& sm, const float* Kt, const float* Wm, const float* al,
                           const float* sT, float* out, int pm, int lb) {
  int tid = threadIdx.x;
  for (int job = lb; job < NT; job += 64) {
    int t = job;
    const float* kr = Kt + (size_t)t * NC;
    const float* wr = Wm + (size_t)t * NC;
    float s1 = 0.0f, s2 = 0.0f;
    for (int c = tid; c < NC; c += 256) {
      float kv = kr[c];
      s1 = fmaf(kv, al[c], s1);
      s2 = fmaf(kv, wr[c], s2);
    }
    for (int off = 32; off; off >>= 1) { s1 += __shfl_down(s1, off); s2 += __shfl_down(s2, off); }
    int wid = tid >> 6, lane = tid & 63;
    __syncthreads();
    if (lane == 0) { sm.red[wid][0] = s1; sm.red[wid][1] = s2; }
    __syncthreads();
    if (tid == 0) {
      s1 = sm.red[0][0] + sm.red[1][0] + sm.red[2][0] + sm.red[3][0];
      s2 = sm.red[0][1] + sm.red[1][1] + sm.red[2][1] + sm.red[3][1];
      out[(size_t)pm * NT + t] = sT[3] + s1;
      out[(size_t)MM * NT + (size_t)pm * NT + t] = sT[13] + sT[14] - s2;
    }
  }
}

// ---------------- mega kernel: 8 independent 64-block partitions -------------
__global__ void __launch_bounds__(256, 2)
mega(const float* xc, const float* yc, const float* xt, float* out, float* ws) {
  __shared__ SMem sm;
  int pm = blockIdx.x >> 6;   // partition = GP index m
  int lb = blockIdx.x & 63;   // local block id within partition
  float* Km = ws + (size_t)pm * 1048576;
  float* Am = ws + OFF_A + (size_t)pm * 1048576;
  float* Tm = ws + OFF_T + (size_t)pm * 262144;
  float* Kt = ws + OFF_KTC + (size_t)pm * NT * NC;
  float* al = ws + OFF_ALPHA + (size_t)pm * 1024;
  float* sT = ws + OFF_SCAL + (size_t)pm * 32;
  unsigned* barm = (unsigned*)(ws + OFF_BAR) + (size_t)pm * 128;
  const float* xm = xc + (size_t)pm * NC * 3;
  const float* ym = yc + (size_t)pm * NC;
  const float* xtm = xt + (size_t)pm * NT * 3;
  float* Wm = Am;  // Am dead after final syrk

  int epoch = 0;
  for (int step = 0; step < 17; ++step) {
    int n = step < 8 ? 512 : 1024;
    int nb = n >> 6;

    ph_buildK(sm, xm, Km, Am, sT, al, n, nb, lb);
    gbar(barm, lb, epoch);

    for (int k = 0; k <= nb - 2; ++k) {
      int t = nb - 1 - k;
      ph_panel(sm, Km, Am, k, n, t, lb);
      gbar(barm, lb, epoch);
      ph_trailF(sm, Km, Am, k, n, t, lb);
      gbar(barm, lb, epoch);
    }
    for (int s2 = 64; s2 < n; s2 <<= 1) {
      ph_trinvT(sm, Km, Am, Tm, s2, n, lb);
      gbar(barm, lb, epoch);
      ph_trinvA(sm, Am, Tm, s2, n, lb);
      gbar(barm, lb, epoch);
    }
    ph_syrk(sm, Am, Km, n, nb, lb);
    gbar(barm, lb, epoch);
    ph_alpha(sm, Km, ym, sT, al, n, nb, lb);
    gbar(barm, lb, epoch);

    if (step < 16) {
      ph_reduce(sm, Km, xm, al, sT, n, nb, lb);
      gbar(barm, lb, epoch);
      ph_adam(sm, Km, ym, al, sT, n, step + 1, lb);
      gbar(barm, lb, epoch);
    }
  }

  ph_buildKtc(sm, xtm, xm, Kt, sT, lb);
  gbar(barm, lb, epoch);
  ph_predW(sm, Kt, Km, Wm, lb);
  gbar(barm, lb, epoch);
  ph_meanvar(sm, Kt, Wm, al, sT, out, pm, lb);
}

// ---------------- init ----------------
__global__ void k_init(float* scal, unsigned* bar) {
  int t = threadIdx.x;
  if (t < MM) {
    float* s = scal + t * 32;
    for (int i = 0; i < 12; ++i) s[i] = 0.0f;
    float sp0 = 0.69314718056f;  // softplus(0)
    s[12] = sp0; s[13] = sp0; s[14] = sp0 + 1e-4f;
    s[15] = 0.0f; s[16] = 0.0f;
  }
  for (int i = t; i < MM * 128; i += 256) bar[i] = 0u;
}

// ---------------- host ----------------
extern "C" void kernel_launch(void* const* d_in, const int* in_sizes, int n_in,
                              void* d_out, int out_size, void* d_ws, size_t ws_size,
                              hipStream_t stream) {
  const float* xc = (const float*)d_in[0];
  const float* yc = (const float*)d_in[1];
  const float* xt = (const float*)d_in[2];
  float* out = (float*)d_out;
  float* ws = (float*)d_ws;
  float* scal = ws + OFF_SCAL;
  unsigned* bar = (unsigned*)(ws + OFF_BAR);

  k_init<<<dim3(1), dim3(256), 0, stream>>>(scal, bar);

  // 512 blocks = 8 partitions x 64; LDS ~47.5KB + 92 VGPR -> >=2 blocks/CU
  // co-resident on 256 CUs, so a plain launch is also safe.
  void* args[5];
  args[0] = (void*)&xc; args[1] = (void*)&yc; args[2] = (void*)&xt;
  args[3] = (void*)&out; args[4] = (void*)&ws;
  hipError_t le = hipLaunchCooperativeKernel(mega, dim3(512), dim3(256), args, 0u, stream);
  if (le != hipSuccess) {
    (void)hipGetLastError();  // clear sticky error; fall back to plain launch
    mega<<<dim3(512), dim3(256), 0, stream>>>(xc, yc, xt, out, ws);
  }

  (void)in_sizes; (void)n_in; (void)out_size; (void)ws_size;
}

// Round 4
// 31137.396 us; speedup vs baseline: 2.8172x; 2.8172x over previous
//
#include <hip/hip_runtime.h>
#include <math.h>

// ---------------- problem constants ----------------
constexpr int MM = 8;      // batch of GPs
constexpr int NC = 1024;   // context points
constexpr int NT = 512;    // target points

// Workspace layout (floats):
//  Kb   : MM*1024*1024   (K -> L panels -> G = K^-1)
//  Ab   : MM*1024*1024   (diag-block inverses + A = L^-1)
//  Tb   : MM*512*512     (trinv temp; reused as S1/S2 accumulators at predict)
//  Ktc  : MM*NT*NC
//  alpha: MM*1024
//  scal : MM*32  per-m: [0..3] raw params [4..7] adam m [8..11] adam v
//                       [12]ls [13]os [14]noise [15]T1 [16]T2 [17]trG
//  bar  : MM*128 u32 (per-m barrier: 4 counters @0/16/32/48, root @64, gen @80)
constexpr size_t OFF_A     = (size_t)MM * 1024 * 1024;
constexpr size_t OFF_T     = OFF_A * 2;
constexpr size_t OFF_KTC   = OFF_T + (size_t)MM * 512 * 512;
constexpr size_t OFF_ALPHA = OFF_KTC + (size_t)MM * NT * NC;
constexpr size_t OFF_SCAL  = OFF_ALPHA + (size_t)MM * 1024;
constexpr size_t OFF_BAR   = OFF_SCAL + (size_t)MM * 32;

#define S5 2.2360679775f

__device__ __forceinline__ float sigmf(float x) { return 1.0f / (1.0f + expf(-x)); }
__device__ __forceinline__ float softplusf(float x) { return fmaxf(x, 0.0f) + log1pf(expf(-fabsf(x))); }

__device__ __forceinline__ void lt_decode(int x, int& i, int& j) {
  int ii = 0;
  while ((ii + 1) * (ii + 2) / 2 <= x) ++ii;
  i = ii; j = x - ii * (ii + 1) / 2;
}

// Shared-memory struct for all phases (~47.5 KB -> 3 blocks/CU at 160 KiB LDS)
struct SMem {
  float Ls[64 * 65];
  float Us[64 * 65];
  float Tt[32 * 33];
  float dvec[64];
  float As[16][68];
  float Bs[16][68];
  float xi[64][3];
  float xj[64][3];
  float ai[64];
  float aj[64];
  float red[4][4];
};

// ---------------- per-m grid barrier --------------------------------------
// KEY FIX vs r3: poll with RELAXED loads (no per-poll cache invalidate);
// a single __threadfence() after exit establishes acquire ordering. The r3
// acquire-poll invalidated L1/L2 every ~700 cycles from every resident block,
// destroying all cache locality (FETCH 7x, phases at HBM latency).
__device__ __forceinline__ void gbar(unsigned* barm, int lb, unsigned per, int& epoch) {
  __syncthreads();
  if (threadIdx.x == 0) {
    unsigned e1 = (unsigned)(epoch + 1);
    __threadfence();  // release: make this block's writes visible device-wide
    unsigned* ctr = barm + ((lb & 3) << 4);  // 64B-padded sub-counters
    unsigned old = __hip_atomic_fetch_add(ctr, 1u, __ATOMIC_RELAXED, __HIP_MEMORY_SCOPE_AGENT);
    if (old + 1u == per * e1) {
      unsigned r = __hip_atomic_fetch_add(barm + 64, 1u, __ATOMIC_RELAXED, __HIP_MEMORY_SCOPE_AGENT);
      if (r + 1u == 4u * e1) {
        __hip_atomic_store(barm + 80, e1, __ATOMIC_RELEASE, __HIP_MEMORY_SCOPE_AGENT);
      }
    }
    while (__hip_atomic_load(barm + 80, __ATOMIC_RELAXED, __HIP_MEMORY_SCOPE_AGENT) < e1) {
      __builtin_amdgcn_s_sleep(4);
    }
    __threadfence();  // acquire: one cache-invalidate per barrier, not per poll
  }
  __syncthreads();
  epoch += 1;
}

// ---------------- 64x64-tile GEMM, register-prefetch double-buffered ---------
// logical A(r,k): TA ? A[k*lda+r] : A[r*lda+k];  logical B(k,c): TB ? B[c*ldb+k] : B[k*ldb+c]
template <int TA, int TB>
__device__ __forceinline__ void gemm64(const float* __restrict__ A, int lda,
                                       const float* __restrict__ B, int ldb,
                                       int kBeg, int kEnd, float acc[4][4], SMem& sm) {
  int tid = threadIdx.x, tx = tid & 15, ty = tid >> 4;
  float ra[4], rb[4];
  auto ldAB = [&](int k0) {
#pragma unroll
    for (int q = 0; q < 4; ++q) {
      int e = tid + (q << 8);
      if (TA) { int kk = e >> 6, r = e & 63; ra[q] = A[(size_t)(k0 + kk) * lda + r]; }
      else    { int r = e >> 4, kk = e & 15; ra[q] = A[(size_t)r * lda + k0 + kk]; }
      if (TB) { int c = e >> 4, kk = e & 15; rb[q] = B[(size_t)c * ldb + k0 + kk]; }
      else    { int kk = e >> 6, c = e & 63; rb[q] = B[(size_t)(k0 + kk) * ldb + c]; }
    }
  };
  ldAB(kBeg);
  for (int k0 = kBeg; k0 < kEnd; k0 += 16) {
    __syncthreads();
#pragma unroll
    for (int q = 0; q < 4; ++q) {
      int e = tid + (q << 8);
      if (TA) sm.As[e >> 6][e & 63] = ra[q]; else sm.As[e & 15][e >> 4] = ra[q];
      if (TB) sm.Bs[e & 15][e >> 4] = rb[q]; else sm.Bs[e >> 6][e & 63] = rb[q];
    }
    __syncthreads();
    if (k0 + 16 < kEnd) ldAB(k0 + 16);  // overlap next tile's loads with compute
#pragma unroll
    for (int kk = 0; kk < 16; ++kk) {
      float a[4], b[4];
#pragma unroll
      for (int i = 0; i < 4; ++i) a[i] = sm.As[kk][ty * 4 + i];
#pragma unroll
      for (int j = 0; j < 4; ++j) b[j] = sm.Bs[kk][tx * 4 + j];
#pragma unroll
      for (int i = 0; i < 4; ++i)
#pragma unroll
        for (int j = 0; j < 4; ++j) acc[i][j] = fmaf(a[i], b[j], acc[i][j]);
    }
  }
}

// ---------------- in-LDS 64x64 SPD factor + triangular inverse ---------------
__device__ void factor64(SMem& sm, float* Uout, int ldu) {
  int tid = threadIdx.x;
  int tx = tid & 15, ty = tid >> 4;
  for (int j = 0; j < 63; ++j) {
    float rinv = 1.0f / sm.Ls[j * 65 + j];
    for (int i = j + 1 + ty; i < 64; i += 16) {
      float lij = sm.Ls[i * 65 + j] * rinv;
      for (int c = j + 1 + tx; c <= i; c += 16) sm.Ls[i * 65 + c] -= lij * sm.Ls[c * 65 + j];
    }
    __syncthreads();
  }
  if (tid < 64) sm.dvec[tid] = 1.0f / sqrtf(sm.Ls[tid * 65 + tid]);
  __syncthreads();
  for (int e = tid; e < 4096; e += 256) { int r = e >> 6, c = e & 63; if (c <= r) sm.Ls[r * 65 + c] *= sm.dvec[c]; }
  __syncthreads();
  for (int e = tid; e < 64 * 65; e += 256) sm.Us[e] = 0.0f;
  __syncthreads();
  if (tid < 64) {
    int b = tid >> 5, c0 = tid & 31, base = b * 32, gc = base + c0;
    sm.Us[gc * 65 + gc] = 1.0f / sm.Ls[gc * 65 + gc];
    for (int r = c0 + 1; r < 32; ++r) {
      int gr = base + r;
      float acc = 0.0f;
      for (int l = c0; l < r; ++l) acc += sm.Ls[gr * 65 + base + l] * sm.Us[(base + l) * 65 + gc];
      sm.Us[gr * 65 + gc] = -acc / sm.Ls[gr * 65 + gr];
    }
  }
  __syncthreads();
  for (int e = tid; e < 1024; e += 256) {
    int r = e >> 5, c = e & 31;
    float acc = 0.0f;
    for (int l = c; l < 32; ++l) acc += sm.Ls[(32 + r) * 65 + l] * sm.Us[l * 65 + c];
    sm.Tt[r * 33 + c] = acc;
  }
  __syncthreads();
  for (int e = tid; e < 1024; e += 256) {
    int r = e >> 5, c = e & 31;
    float acc = 0.0f;
    for (int l = 0; l <= r; ++l) acc += sm.Us[(32 + r) * 65 + 32 + l] * sm.Tt[l * 33 + c];
    sm.Us[(32 + r) * 65 + c] = -acc;
  }
  __syncthreads();
  for (int e = tid; e < 4096; e += 256) { int r = e >> 6, c = e & 63; Uout[(size_t)r * ldu + c] = sm.Us[r * 65 + c]; }
}

// ---------------- phases (per-m partition of nbp blocks, local id lb) --------

__device__ void ph_buildK(SMem& sm, const float* xm, float* Km, float* Am,
                          float* sT, float* al, int n, int nb, int lb, int nbp) {
  int tid = threadIdx.x;
  {
    int zi = (lb - 1) * 256 + tid;
    if (lb >= 1 && lb <= 4 && zi < n) al[zi] = 0.0f;
    if (lb == 5 && tid < 3) sT[15 + tid] = 0.0f;
  }
  float ls = sT[12], os = sT[13], noi = sT[14];
  float il2 = 1.0f / (ls * ls);
  int njobs = nb * (nb + 1) / 2;
  for (int job = lb; job < njobs; job += nbp) {
    int bi, bj; lt_decode(job, bi, bj);
    __syncthreads();
    if (tid < 64) {
      int r = bi * 64 + tid;
      sm.xi[tid][0] = xm[r * 3 + 0]; sm.xi[tid][1] = xm[r * 3 + 1]; sm.xi[tid][2] = xm[r * 3 + 2];
    } else if (tid < 128) {
      int lr = tid - 64; int r = bj * 64 + lr;
      sm.xj[lr][0] = xm[r * 3 + 0]; sm.xj[lr][1] = xm[r * 3 + 1]; sm.xj[lr][2] = xm[r * 3 + 2];
    }
    __syncthreads();
    if (job == 0) {
      for (int e = tid; e < 4096; e += 256) {
        int r = e >> 6, c = e & 63;
        float d0 = sm.xi[r][0] - sm.xj[c][0], d1 = sm.xi[r][1] - sm.xj[c][1], d2 = sm.xi[r][2] - sm.xj[c][2];
        float r2 = d0 * d0 + d1 * d1 + d2 * d2;
        float z = fmaxf(r2 * il2, 1e-12f);
        float dd = sqrtf(z);
        float kv = os * (1.0f + S5 * dd + (5.0f / 3.0f) * z) * expf(-S5 * dd);
        if (r == c) kv += noi;
        sm.Ls[r * 65 + c] = kv;
      }
      __syncthreads();
      factor64(sm, Am, n);
    } else {
      for (int e = tid; e < 4096; e += 256) {
        int r = e >> 6, c = e & 63;
        float d0 = sm.xi[r][0] - sm.xj[c][0], d1 = sm.xi[r][1] - sm.xj[c][1], d2 = sm.xi[r][2] - sm.xj[c][2];
        float r2 = d0 * d0 + d1 * d1 + d2 * d2;
        float z = fmaxf(r2 * il2, 1e-12f);
        float dd = sqrtf(z);
        float kv = os * (1.0f + S5 * dd + (5.0f / 3.0f) * z) * expf(-S5 * dd);
        if (bi == bj && r == c) kv += noi;
        Km[(size_t)(bi * 64 + r) * n + bj * 64 + c] = kv;
      }
    }
  }
}

__device__ void ph_panel(SMem& sm, float* Km, const float* Am, int k, int n, int t, int lb, int nbp) {
  int tx = threadIdx.x & 15, ty = threadIdx.x >> 4;
  for (int job = lb; job < t; job += nbp) {
    int i = k + 1 + job;
    float acc[4][4] = {};
    gemm64<0, 1>(Km + (size_t)(i * 64) * n + k * 64, n,
                 Am + (size_t)(k * 64) * n + k * 64, n, 0, 64, acc, sm);
    float* C = Km + (size_t)(i * 64) * n + k * 64;
#pragma unroll
    for (int ii = 0; ii < 4; ++ii)
#pragma unroll
      for (int jj = 0; jj < 4; ++jj) C[(size_t)(ty * 4 + ii) * n + tx * 4 + jj] = acc[ii][jj];
  }
}

// trail: K[i,j] -= L[i,k]*L[j,k]^T; job 0 = tile (k+1,k+1): update in LDS and
// immediately factor+invert (fused diag, overlapped with other jobs)
__device__ void ph_trailF(SMem& sm, float* Km, float* Am, int k, int n, int t, int lb, int nbp) {
  int tx = threadIdx.x & 15, ty = threadIdx.x >> 4;
  int njobs = t * (t + 1) / 2;
  for (int job = lb; job < njobs; job += nbp) {
    int di, dj; lt_decode(job, di, dj);
    int i = k + 1 + di, j = k + 1 + dj;
    float acc[4][4] = {};
    gemm64<0, 1>(Km + (size_t)(i * 64) * n + k * 64, n,
                 Km + (size_t)(j * 64) * n + k * 64, n, 0, 64, acc, sm);
    float* C = Km + (size_t)(i * 64) * n + j * 64;
    if (job == 0) {
#pragma unroll
      for (int ii = 0; ii < 4; ++ii)
#pragma unroll
        for (int jj = 0; jj < 4; ++jj)
          sm.Ls[(ty * 4 + ii) * 65 + tx * 4 + jj] =
              C[(size_t)(ty * 4 + ii) * n + tx * 4 + jj] - acc[ii][jj];
      __syncthreads();
      factor64(sm, Am + (size_t)((k + 1) * 64) * n + (k + 1) * 64, n);
    } else {
#pragma unroll
      for (int ii = 0; ii < 4; ++ii)
#pragma unroll
        for (int jj = 0; jj < 4; ++jj)
          C[(size_t)(ty * 4 + ii) * n + tx * 4 + jj] -= acc[ii][jj];
    }
  }
}

__device__ void ph_trinvT(SMem& sm, const float* Km, const float* Am, float* Tm,
                          int s, int n, int lb, int nbp) {
  int tx = threadIdx.x & 15, ty = threadIdx.x >> 4;
  int st = s >> 6, np = n / (2 * s);
  int njobs = np * st * st;
  for (int job = lb; job < njobs; job += nbp) {
    int p = job / (st * st), rem = job % (st * st);
    int ti = rem / st, tj = rem % st;
    int base = p * 2 * s;
    float acc[4][4] = {};
    gemm64<0, 0>(Km + (size_t)(base + s + ti * 64) * n + base, n,
                 Am + (size_t)base * n + base + tj * 64, n, tj * 64, s, acc, sm);
    float* C = Tm + (size_t)p * s * s + (size_t)(ti * 64) * s + tj * 64;
#pragma unroll
    for (int ii = 0; ii < 4; ++ii)
#pragma unroll
      for (int jj = 0; jj < 4; ++jj) C[(size_t)(ty * 4 + ii) * s + tx * 4 + jj] = acc[ii][jj];
  }
}

__device__ void ph_trinvA(SMem& sm, float* Am, const float* Tm, int s, int n, int lb, int nbp) {
  int tx = threadIdx.x & 15, ty = threadIdx.x >> 4;
  int st = s >> 6, np = n / (2 * s);
  int njobs = np * st * st;
  for (int job = lb; job < njobs; job += nbp) {
    int p = job / (st * st), rem = job % (st * st);
    int ti = rem / st, tj = rem % st;
    int base = p * 2 * s;
    float acc[4][4] = {};
    gemm64<0, 0>(Am + (size_t)(base + s + ti * 64) * n + base + s, n,
                 Tm + (size_t)p * s * s + tj * 64, s, 0, (ti + 1) * 64, acc, sm);
    float* C = Am + (size_t)(base + s + ti * 64) * n + base + tj * 64;
#pragma unroll
    for (int ii = 0; ii < 4; ++ii)
#pragma unroll
      for (int jj = 0; jj < 4; ++jj) C[(size_t)(ty * 4 + ii) * n + tx * 4 + jj] = -acc[ii][jj];
  }
}

// syrk + fused alpha (+= G*(y-c)) + fused tr(G): G = A^T A, lower + mirror
__device__ void ph_syrkAT(SMem& sm, const float* Am, float* Gm, const float* ym,
                          float* sT, float* al, int n, int nb, int lb, int nbp) {
  int tid = threadIdx.x, tx = tid & 15, ty = tid >> 4;
  float cm = sT[3];
  int njobs = nb * (nb + 1) / 2;
  for (int job = lb; job < njobs; job += nbp) {
    int ib, jb; lt_decode(job, ib, jb);
    __syncthreads();
    if (tid < 64) sm.ai[tid] = ym[ib * 64 + tid] - cm;
    else if (tid < 128) sm.aj[tid - 64] = ym[jb * 64 + tid - 64] - cm;
    float acc[4][4] = {};
    gemm64<1, 0>(Am + ib * 64, n, Am + jb * 64, n, ib * 64, n, acc, sm);
#pragma unroll
    for (int ii = 0; ii < 4; ++ii)
#pragma unroll
      for (int jj = 0; jj < 4; ++jj) {
        int r = ty * 4 + ii, c = tx * 4 + jj;
        Gm[(size_t)(ib * 64 + r) * n + jb * 64 + c] = acc[ii][jj];
        if (ib != jb) Gm[(size_t)(jb * 64 + c) * n + ib * 64 + r] = acc[ii][jj];
      }
    if (ib == jb && tx == ty) {
      float td = acc[0][0] + acc[1][1] + acc[2][2] + acc[3][3];
      atomicAdd(&sT[17], td);
    }
    // alpha rows (ib-block): rowp[i] = sum_j acc[i][j] * d[jb*64 + tx*4+j]
    float rowp[4];
#pragma unroll
    for (int i = 0; i < 4; ++i) {
      float s = 0.0f;
#pragma unroll
      for (int j = 0; j < 4; ++j) s = fmaf(acc[i][j], sm.aj[tx * 4 + j], s);
      rowp[i] = s;
    }
    float colp[4];
    if (ib != jb) {
#pragma unroll
      for (int j = 0; j < 4; ++j) {
        float s = 0.0f;
#pragma unroll
        for (int i = 0; i < 4; ++i) s = fmaf(acc[i][j], sm.ai[ty * 4 + i], s);
        colp[j] = s;
      }
    }
    __syncthreads();  // gemm LDS reads done; reuse As/Bs as reduction scratch
    float* redA = &sm.As[0][0];
    float* redB = &sm.Bs[0][0];
#pragma unroll
    for (int i = 0; i < 4; ++i) redA[(ty * 4 + i) * 16 + tx] = rowp[i];
    if (ib != jb) {
#pragma unroll
      for (int j = 0; j < 4; ++j) redB[(tx * 4 + j) * 16 + ty] = colp[j];
    }
    __syncthreads();
    if (tid < 64) {
      float s = 0.0f;
#pragma unroll
      for (int q = 0; q < 16; ++q) s += redA[tid * 16 + q];
      atomicAdd(&al[ib * 64 + tid], s);
      if (ib != jb) {
        float s2 = 0.0f;
#pragma unroll
        for (int q = 0; q < 16; ++q) s2 += redB[tid * 16 + q];
        atomicAdd(&al[jb * 64 + tid], s2);
      }
    }
  }
}

// reduce: T1 = sum G.*C, T2 = alpha^T C alpha (lower-tri tiles, weight 2 off-diag)
__device__ void ph_reduce(SMem& sm, const float* Gm, const float* xm, const float* al,
                          float* sT, int n, int nb, int lb, int nbp) {
  int tid = threadIdx.x;
  int njobs = nb * (nb + 1) / 2;
  float ls = sT[12], os = sT[13];
  float il2 = 1.0f / (ls * ls);
  float c53 = (5.0f / 3.0f) * os / ls;
  for (int job = lb; job < njobs; job += nbp) {
    int bi, bj; lt_decode(job, bi, bj);
    float w = (bi == bj) ? 1.0f : 2.0f;
    __syncthreads();
    if (tid < 64) {
      int r = bi * 64 + tid;
      sm.xi[tid][0] = xm[r * 3 + 0]; sm.xi[tid][1] = xm[r * 3 + 1]; sm.xi[tid][2] = xm[r * 3 + 2];
      sm.ai[tid] = al[r];
    } else if (tid < 128) {
      int lr = tid - 64; int r = bj * 64 + lr;
      sm.xj[lr][0] = xm[r * 3 + 0]; sm.xj[lr][1] = xm[r * 3 + 1]; sm.xj[lr][2] = xm[r * 3 + 2];
      sm.aj[lr] = al[r];
    }
    __syncthreads();
    float a1 = 0.0f, a2 = 0.0f;
    for (int e = tid; e < 4096; e += 256) {
      int r = e >> 6, c = e & 63;
      float d0 = sm.xi[r][0] - sm.xj[c][0], d1 = sm.xi[r][1] - sm.xj[c][1], d2 = sm.xi[r][2] - sm.xj[c][2];
      float r2 = d0 * d0 + d1 * d1 + d2 * d2;
      float z = fmaxf(r2 * il2, 1e-12f);
      float dd = sqrtf(z);
      float Cv = c53 * z * (1.0f + S5 * dd) * expf(-S5 * dd);
      float g = Gm[(size_t)(bi * 64 + r) * n + bj * 64 + c];
      a1 = fmaf(g, Cv, a1);
      a2 = fmaf(sm.ai[r] * sm.aj[c], Cv, a2);
    }
    a1 *= w; a2 *= w;
    for (int off = 32; off; off >>= 1) { a1 += __shfl_down(a1, off); a2 += __shfl_down(a2, off); }
    int wid = tid >> 6, lane = tid & 63;
    if (lane == 0) { sm.red[wid][0] = a1; sm.red[wid][1] = a2; }
    __syncthreads();
    if (tid == 0) {
      a1 = sm.red[0][0] + sm.red[1][0] + sm.red[2][0] + sm.red[3][0];
      a2 = sm.red[0][1] + sm.red[1][1] + sm.red[2][1] + sm.red[3][1];
      atomicAdd(&sT[15], a1);
      atomicAdd(&sT[16], a2);
    }
  }
}

// adam: alpha-based sums (trG precomputed in syrk), grads, param update
__device__ void ph_adam(SMem& sm, const float* ym, const float* al,
                        float* sT, int n, int tstep, int lb) {
  if (lb != 0) return;
  int tid = threadIdx.x;
  float cm = sT[3];
  float t4 = 0, t5 = 0, t6 = 0;
  for (int i = tid; i < n; i += 256) {
    float a = al[i];
    t4 = fmaf(a, a, t4);
    t5 += a;
    t6 = fmaf(ym[i] - cm, a, t6);
  }
  for (int off = 32; off; off >>= 1) {
    t4 += __shfl_down(t4, off); t5 += __shfl_down(t5, off); t6 += __shfl_down(t6, off);
  }
  int wid = tid >> 6, lane = tid & 63;
  __syncthreads();
  if (lane == 0) { sm.red[wid][0] = t4; sm.red[wid][1] = t5; sm.red[wid][2] = t6; }
  __syncthreads();
  if (tid == 0) {
    t4 = sm.red[0][0] + sm.red[1][0] + sm.red[2][0] + sm.red[3][0];
    t5 = sm.red[0][1] + sm.red[1][1] + sm.red[2][1] + sm.red[3][1];
    t6 = sm.red[0][2] + sm.red[1][2] + sm.red[2][2] + sm.red[3][2];
    float t3 = sT[17];
    float T1 = sT[15], T2 = sT[16];
    float ls = sT[12], os = sT[13], noi = sT[14];
    float fn = (float)n;
    float g_ls = 0.5f / fn * (T1 - T2);
    float g_os = 0.5f / (fn * os) * (fn - noi * t3 - t6 + noi * t4);
    float g_no = 0.5f / fn * (t3 - t4);
    float g_c  = -t5 / fn;
    float gr[4];
    gr[0] = g_ls * sigmf(sT[0]);
    gr[1] = g_os * sigmf(sT[1]);
    gr[2] = g_no * sigmf(sT[2]);
    gr[3] = g_c;
    float bc1 = 1.0f - powf(0.9f, (float)tstep);
    float bc2 = 1.0f - powf(0.999f, (float)tstep);
#pragma unroll
    for (int i = 0; i < 4; ++i) {
      float mv = 0.9f * sT[4 + i] + 0.1f * gr[i];
      float vv = 0.999f * sT[8 + i] + 0.001f * gr[i] * gr[i];
      sT[4 + i] = mv; sT[8 + i] = vv;
      sT[i] = sT[i] - 0.1f * (mv / bc1) / (sqrtf(vv / bc2) + 1e-8f);
    }
    sT[12] = softplusf(sT[0]);
    sT[13] = softplusf(sT[1]);
    sT[14] = softplusf(sT[2]) + 1e-4f;
  }
}

// prediction
__device__ void ph_buildKtc(SMem& sm, const float* xtm, const float* xm, float* Kt,
                            const float* sT, float* S1, float* S2, int lb, int nbp) {
  int tid = threadIdx.x;
  {
    int z = lb * 256 + tid;
    if (z < NT) { S1[z] = 0.0f; S2[z] = 0.0f; }
  }
  float ls = sT[12], os = sT[13];
  float il2 = 1.0f / (ls * ls);
  int njobs = (NT / 64) * (NC / 64);  // 128
  for (int job = lb; job < njobs; job += nbp) {
    int ti = job >> 4, tj = job & 15;
    __syncthreads();
    if (tid < 64) {
      int r = ti * 64 + tid;
      sm.xi[tid][0] = xtm[r * 3 + 0]; sm.xi[tid][1] = xtm[r * 3 + 1]; sm.xi[tid][2] = xtm[r * 3 + 2];
    } else if (tid < 128) {
      int lr = tid - 64; int r = tj * 64 + lr;
      sm.xj[lr][0] = xm[r * 3 + 0]; sm.xj[lr][1] = xm[r * 3 + 1]; sm.xj[lr][2] = xm[r * 3 + 2];
    }
    __syncthreads();
    for (int e = tid; e < 4096; e += 256) {
      int r = e >> 6, c = e & 63;
      float d0 = sm.xi[r][0] - sm.xj[c][0], d1 = sm.xi[r][1] - sm.xj[c][1], d2 = sm.xi[r][2] - sm.xj[c][2];
      float r2 = d0 * d0 + d1 * d1 + d2 * d2;
      float z = fmaxf(r2 * il2, 1e-12f);
      float dd = sqrtf(z);
      float kv = os * (1.0f + S5 * dd + (5.0f / 3.0f) * z) * expf(-S5 * dd);
      Kt[(size_t)(ti * 64 + r) * NC + tj * 64 + c] = kv;
    }
  }
}

// W-tile = Ktc*G computed in-register; fused partials: S1 += Ktc.alpha, S2 += Ktc.W
__device__ void ph_predW(SMem& sm, const float* Kt, const float* Gm, const float* al,
                         float* S1, float* S2, int lb, int nbp) {
  int tid = threadIdx.x, tx = tid & 15, ty = tid >> 4;
  int njobs = (NT / 64) * (NC / 64);
  for (int job = lb; job < njobs; job += nbp) {
    int ti = job >> 4, tj = job & 15;
    __syncthreads();
    if (tid < 64) sm.aj[tid] = al[tj * 64 + tid];
    float acc[4][4] = {};
    gemm64<0, 0>(Kt + (size_t)(ti * 64) * NC, NC, Gm + tj * 64, 1024, 0, 1024, acc, sm);
    float s1p[4], s2p[4];
#pragma unroll
    for (int i = 0; i < 4; ++i) {
      float a1 = 0.0f, a2 = 0.0f;
      const float* kr = Kt + (size_t)(ti * 64 + ty * 4 + i) * NC + tj * 64;
#pragma unroll
      for (int j = 0; j < 4; ++j) {
        float kv = kr[tx * 4 + j];
        a1 = fmaf(kv, sm.aj[tx * 4 + j], a1);
        a2 = fmaf(kv, acc[i][j], a2);
      }
      s1p[i] = a1; s2p[i] = a2;
    }
    __syncthreads();
    float* redA = &sm.As[0][0];
    float* redB = &sm.Bs[0][0];
#pragma unroll
    for (int i = 0; i < 4; ++i) {
      redA[(ty * 4 + i) * 16 + tx] = s1p[i];
      redB[(ty * 4 + i) * 16 + tx] = s2p[i];
    }
    __syncthreads();
    if (tid < 64) {
      float a1 = 0.0f, a2 = 0.0f;
#pragma unroll
      for (int q = 0; q < 16; ++q) { a1 += redA[tid * 16 + q]; a2 += redB[tid * 16 + q]; }
      atomicAdd(&S1[ti * 64 + tid], a1);
      atomicAdd(&S2[ti * 64 + tid], a2);
    }
  }
}

__device__ void ph_finalize(const float* S1, const float* S2, const float* sT,
                            float* out, int pm, int lb) {
  int t = lb * 256 + threadIdx.x;
  if (t < NT) {
    out[(size_t)pm * NT + t] = sT[3] + S1[t];
    out[(size_t)MM * NT + (size_t)pm * NT + t] = sT[13] + sT[14] - S2[t];
  }
}

// ---------------- mega kernel: 8 XCD-pinned partitions -----------------------
__global__ void __launch_bounds__(256, 3)
mega(const float* xc, const float* yc, const float* xt, float* out, float* ws, int nbp) {
  __shared__ SMem sm;
  // partition = blockIdx % 8: with round-robin block->XCD dispatch this pins
  // each GP's working set to one XCD's L2 (locality heuristic, not correctness)
  int pm = blockIdx.x & 7;
  int lb = blockIdx.x >> 3;
  float* Km = ws + (size_t)pm * 1048576;
  float* Am = ws + OFF_A + (size_t)pm * 1048576;
  float* Tm = ws + OFF_T + (size_t)pm * 262144;
  float* Kt = ws + OFF_KTC + (size_t)pm * NT * NC;
  float* al = ws + OFF_ALPHA + (size_t)pm * 1024;
  float* sT = ws + OFF_SCAL + (size_t)pm * 32;
  unsigned* barm = (unsigned*)(ws + OFF_BAR) + (size_t)pm * 128;
  const float* xm = xc + (size_t)pm * NC * 3;
  const float* ym = yc + (size_t)pm * NC;
  const float* xtm = xt + (size_t)pm * NT * 3;
  float* S1 = Tm;          // Tm free at predict time
  float* S2 = Tm + NT;
  unsigned per = (unsigned)(nbp >> 2);

  int epoch = 0;
  for (int step = 0; step < 17; ++step) {
    int n = step < 8 ? 512 : 1024;
    int nb = n >> 6;

    ph_buildK(sm, xm, Km, Am, sT, al, n, nb, lb, nbp);
    gbar(barm, lb, per, epoch);

    for (int k = 0; k <= nb - 2; ++k) {
      int t = nb - 1 - k;
      ph_panel(sm, Km, Am, k, n, t, lb, nbp);
      gbar(barm, lb, per, epoch);
      ph_trailF(sm, Km, Am, k, n, t, lb, nbp);
      gbar(barm, lb, per, epoch);
    }
    for (int s2 = 64; s2 < n; s2 <<= 1) {
      ph_trinvT(sm, Km, Am, Tm, s2, n, lb, nbp);
      gbar(barm, lb, per, epoch);
      ph_trinvA(sm, Am, Tm, s2, n, lb, nbp);
      gbar(barm, lb, per, epoch);
    }
    ph_syrkAT(sm, Am, Km, ym, sT, al, n, nb, lb, nbp);
    gbar(barm, lb, per, epoch);

    if (step < 16) {
      ph_reduce(sm, Km, xm, al, sT, n, nb, lb, nbp);
      gbar(barm, lb, per, epoch);
      ph_adam(sm, ym, al, sT, n, step + 1, lb);
      gbar(barm, lb, per, epoch);
    }
  }

  ph_buildKtc(sm, xtm, xm, Kt, sT, S1, S2, lb, nbp);
  gbar(barm, lb, per, epoch);
  ph_predW(sm, Kt, Km, al, S1, S2, lb, nbp);
  gbar(barm, lb, per, epoch);
  ph_finalize(S1, S2, sT, out, pm, lb);
}

// ---------------- init ----------------
__global__ void k_init(float* scal, unsigned* bar) {
  int t = threadIdx.x;
  if (t < MM) {
    float* s = scal + t * 32;
    for (int i = 0; i < 12; ++i) s[i] = 0.0f;
    float sp0 = 0.69314718056f;  // softplus(0)
    s[12] = sp0; s[13] = sp0; s[14] = sp0 + 1e-4f;
    s[15] = 0.0f; s[16] = 0.0f; s[17] = 0.0f;
  }
  for (int i = t; i < MM * 128; i += 256) bar[i] = 0u;
}

// ---------------- host ----------------
extern "C" void kernel_launch(void* const* d_in, const int* in_sizes, int n_in,
                              void* d_out, int out_size, void* d_ws, size_t ws_size,
                              hipStream_t stream) {
  const float* xc = (const float*)d_in[0];
  const float* yc = (const float*)d_in[1];
  const float* xt = (const float*)d_in[2];
  float* out = (float*)d_out;
  float* ws = (float*)d_ws;
  float* scal = ws + OFF_SCAL;
  unsigned* bar = (unsigned*)(ws + OFF_BAR);

  k_init<<<dim3(1), dim3(256), 0, stream>>>(scal, bar);

  // blocks/CU from occupancy query (host-side, capture-safe); co-residency is
  // required for the spin barrier. launch_bounds(256,3) + 47.5KB LDS -> 3/CU.
  int maxb = 0;
  hipError_t qe = hipOccupancyMaxActiveBlocksPerMultiprocessor(&maxb, mega, 256, 0);
  if (qe != hipSuccess || maxb < 2) maxb = 2;
  if (maxb > 3) maxb = 3;
  int nbp = 32 * maxb;        // blocks per partition (multiple of 4)
  int grid = 8 * nbp;

  void* args[6];
  args[0] = (void*)&xc; args[1] = (void*)&yc; args[2] = (void*)&xt;
  args[3] = (void*)&out; args[4] = (void*)&ws; args[5] = (void*)&nbp;
  hipError_t le = hipLaunchCooperativeKernel(mega, dim3(grid), dim3(256), args, 0u, stream);
  if (le != hipSuccess) {
    (void)hipGetLastError();  // clear sticky error; plain launch (co-resident by occupancy)
    mega<<<dim3(grid), dim3(256), 0, stream>>>(xc, yc, xt, out, ws, nbp);
  }

  (void)in_sizes; (void)n_in; (void)out_size; (void)ws_size;
}